// Round 8
// baseline (137.132 us; speedup 1.0000x reference)
//
#include <hip/hip_runtime.h>
#include <hip/hip_bf16.h>
#include <stdint.h>

#define G_ 24
#define B_ 256
#define I_ 512
#define E_ 512
#define K_ (G_ * I_)   // 12288
// BM=256 (full M), BN=256, BK=64, splitK=4 -> grid 192 = 2n x 24h x 4s, 1 WG/CU.

typedef __hip_bfloat16 bf16;
typedef __bf16 bf16x8 __attribute__((ext_vector_type(8)));
typedef float f32x4 __attribute__((ext_vector_type(4)));

// ---------- input f32 -> bf16 ----------
__global__ void cvt_in_kernel(const float* __restrict__ in, bf16* __restrict__ out, int n4) {
  int idx = blockIdx.x * blockDim.x + threadIdx.x;
  if (idx >= n4) return;
  float4 v = reinterpret_cast<const float4*>(in)[idx];
  union { bf16 h[4]; uint2 u; } pk;
  pk.h[0] = __float2bfloat16(v.x);
  pk.h[1] = __float2bfloat16(v.y);
  pk.h[2] = __float2bfloat16(v.z);
  pk.h[3] = __float2bfloat16(v.w);
  reinterpret_cast<uint2*>(out)[idx] = pk.u;
}

// ---------- W[g][i][e] f32 -> Wt[g][e][i] bf16 ----------
__global__ void transpose_w_kernel(const float* __restrict__ W, bf16* __restrict__ Wt) {
  __shared__ float tile[32][33];
  const int g = blockIdx.z;
  const int i0 = blockIdx.x * 32;
  const int e0 = blockIdx.y * 32;
  const float* src = W + (size_t)g * (I_ * E_) + (size_t)(i0 + threadIdx.y) * E_ + e0 + threadIdx.x;
  #pragma unroll
  for (int r = 0; r < 32; r += 8)
    tile[threadIdx.y + r][threadIdx.x] = src[(size_t)r * E_];
  __syncthreads();
  bf16* dst = Wt + (size_t)g * (I_ * E_) + (size_t)(e0 + threadIdx.y) * I_ + i0 + threadIdx.x;
  #pragma unroll
  for (int r = 0; r < 32; r += 8)
    dst[(size_t)r * I_] = __float2bfloat16(tile[threadIdx.x][threadIdx.y + r]);
}

// ---------- out[b][h][e] = bias[e] ----------
__global__ void init_out_kernel(const float* __restrict__ bias, float* __restrict__ out, int n4) {
  int idx = blockIdx.x * blockDim.x + threadIdx.x;
  if (idx >= n4) return;
  int e4 = idx & 127;  // (E/4)=128 float4 per (b,h) row
  reinterpret_cast<float4*>(out)[idx] = reinterpret_cast<const float4*>(bias)[e4];
}

// ================= GEMM: BM=256(full), BN=256, BK=64, 8 waves of 128x64, splitK=4 =================
// out[b,h,e] += sum_k A[b,k] * Wt[(k/512 - h)%24][e][k%512]
// Staging-BW roofline design: FLOP per staged byte = 256*256/(256+256) = 131
// (vs 64 for 128^2) -> total staged 0.59 GB; at the empirically-invariant
// ~11 TB/s global->LDS staging rate x 0.75 CU coverage => ~65 us gemm.
// Proven 2-barrier counted-vmcnt loop (the schedule that sustains 10+ TB/s;
// the 8-phase ports throttled staging to 5-6 TB/s and lost).
// XCD pin: xcd = bid&7 <-> (n-half, split); h = bid>>3. Per-XCD per-step
// W set = 24 gsrc x 32 KB = 0.77 MB + one shared 32 KB A window -> L2-clean.
// XOR slot-swizzle both sides (16B granule, 8 slots/row, row&7).
#define FENCE() asm volatile("" ::: "memory")
#define BAR()   __builtin_amdgcn_s_barrier()
#define VMW(N)  asm volatile("s_waitcnt vmcnt(" #N ")" ::: "memory")

__device__ __forceinline__ void gload16(const bf16* g, bf16* l) {
  __builtin_amdgcn_global_load_lds((const __attribute__((address_space(1))) void*)g,
                                   (__attribute__((address_space(3))) void*)l, 16, 0, 0);
}

__global__ __launch_bounds__(512, 2) void gemm256_kernel(
    const bf16* __restrict__ A,   // [256][12288]
    const bf16* __restrict__ Wt,  // [24][512(e)][512(i)]
    float* __restrict__ out) {    // [256][24][512], pre-init'd with bias

  __shared__ __align__(16) bf16 lds[2][2][256 * 64];  // [buf][A/B] = 128 KB

  const int tid  = threadIdx.x;        // 0..511
  const int lane = tid & 63;
  const int wave = tid >> 6;           // 0..7
  const int wr   = wave >> 2;          // 0..1 -> 128 M-rows
  const int wc   = wave & 3;           // 0..3 -> 64 N-cols
  const int rsel = lane & 15;
  const int q    = lane >> 4;          // 0..3

  // XCD-pinned decode: xcd = bid&7 -> (n-half, split); h = bid>>3.
  const int bid   = blockIdx.x;        // 0..191
  const int xcd   = bid & 7;
  const int n0    = (xcd & 1) * 256;
  const int s     = xcd >> 1;          // split 0..3
  const int h     = bid >> 3;          // 0..23
  const int T0    = s * 48;            // k-tile (BK=64) start; 48 tiles per split

  // ---- loop-invariant staging offsets (4 chunks per thread per operand) ----
  // chunk c (0..2047): row = c>>3, linear slot = c&7, source slot = (c&7)^(row&7)
  size_t aoff[4], boff[4];
  int ldso[4];
  #pragma unroll
  for (int j = 0; j < 4; ++j) {
    int c    = tid + j * 512;
    int row  = c >> 3;
    int slot = (c & 7) ^ (row & 7);
    aoff[j] = (size_t)row * K_ + slot * 8;
    boff[j] = (size_t)row * I_ + slot * 8;
    ldso[j] = c * 8;
  }

  // ---- loop-invariant ds_read byte offsets (kk=0; kk=1 is ^64) ----
  int aro[8], bro[4];
  #pragma unroll
  for (int mi = 0; mi < 8; ++mi) {
    int r = wr * 128 + mi * 16 + rsel;
    aro[mi] = r * 128 + ((q ^ (r & 7)) << 4);
  }
  #pragma unroll
  for (int ni = 0; ni < 4; ++ni) {
    int r = wc * 64 + ni * 16 + rsel;
    bro[ni] = r * 128 + ((q ^ (r & 7)) << 4);
  }

  f32x4 acc[8][4];
  #pragma unroll
  for (int i = 0; i < 8; ++i)
    #pragma unroll
    for (int j = 0; j < 4; ++j)
      acc[i][j] = (f32x4){0.f, 0.f, 0.f, 0.f};

  // stage k-tile t into buffer b
  auto stage = [&](int t, int b) {
    int g = t >> 3;                    // 0..23
    int gsrc = g - h; if (gsrc < 0) gsrc += G_;
    const int i0 = (t & 7) * 64;
    const bf16* Ab = A + (size_t)t * 64;
    const bf16* Bb = Wt + (size_t)gsrc * (I_ * E_) + (size_t)n0 * I_ + i0;
    #pragma unroll
    for (int j = 0; j < 4; ++j)
      gload16(Ab + aoff[j], &lds[b][0][ldso[j]]);
    #pragma unroll
    for (int j = 0; j < 4; ++j)
      gload16(Bb + boff[j], &lds[b][1][ldso[j]]);
  };

  stage(T0, 0);

  for (int lt = 0; lt < 48; ++lt) {
    const int cur = lt & 1;
    if (lt + 1 < 48) {
      stage(T0 + lt + 1, cur ^ 1);
      VMW(8);  // retire stage(t); keep stage(t+1)'s 8 loads in flight
    } else {
      VMW(0);
    }
    FENCE(); BAR(); FENCE();

    const char* Al = (const char*)&lds[cur][0][0];
    const char* Bl = (const char*)&lds[cur][1][0];
    #pragma unroll
    for (int kk = 0; kk < 2; ++kk) {
      const int x = kk << 6;  // kk=1 -> XOR 64 on byte offset
      bf16x8 af[8], bfr[4];
      #pragma unroll
      for (int mi = 0; mi < 8; ++mi)
        af[mi] = *(const bf16x8*)(Al + (aro[mi] ^ x));
      #pragma unroll
      for (int ni = 0; ni < 4; ++ni)
        bfr[ni] = *(const bf16x8*)(Bl + (bro[ni] ^ x));
      #pragma unroll
      for (int mi = 0; mi < 8; ++mi)
        #pragma unroll
        for (int ni = 0; ni < 4; ++ni)
          acc[mi][ni] = __builtin_amdgcn_mfma_f32_16x16x32_bf16(
              af[mi], bfr[ni], acc[mi][ni], 0, 0, 0);
    }

    asm volatile("s_waitcnt lgkmcnt(0)" ::: "memory");
    BAR(); FENCE();
  }

  // ---- epilogue: atomic split-K combine. C/D: col=lane&15, row=(lane>>4)*4+reg
  #pragma unroll
  for (int mi = 0; mi < 8; ++mi) {
    #pragma unroll
    for (int ni = 0; ni < 4; ++ni) {
      int ecol  = n0 + wc * 64 + ni * 16 + rsel;
      int brow0 = wr * 128 + mi * 16 + q * 4;
      float* o = out + (size_t)brow0 * (G_ * E_) + (size_t)h * E_ + ecol;
      #pragma unroll
      for (int r = 0; r < 4; ++r)
        atomicAdd(o + (size_t)r * (G_ * E_), acc[mi][ni][r]);
    }
  }
}

extern "C" void kernel_launch(void* const* d_in, const int* in_sizes, int n_in,
                              void* d_out, int out_size, void* d_ws, size_t ws_size,
                              hipStream_t stream) {
  const float* in   = (const float*)d_in[0];
  const float* w    = (const float*)d_in[1];
  const float* bias = (const float*)d_in[2];
  float* out = (float*)d_out;

  bf16* A_bf = (bf16*)d_ws;                                   // 6.29 MB
  bf16* Wt   = (bf16*)((char*)d_ws + (size_t)B_ * K_ * 2);    // 12.58 MB

  const int n4in  = (B_ * K_) / 4;        // 786432
  const int n4out = (B_ * G_ * E_) / 4;   // 786432
  cvt_in_kernel<<<n4in / 256, 256, 0, stream>>>(in, A_bf, n4in);
  transpose_w_kernel<<<dim3(E_ / 32, I_ / 32, G_), dim3(32, 8), 0, stream>>>(w, Wt);
  init_out_kernel<<<n4out / 256, 256, 0, stream>>>(bias, out, n4out);
  gemm256_kernel<<<192, 512, 0, stream>>>(A_bf, Wt, out);
}